// Round 2
// baseline (205.934 us; speedup 1.0000x reference)
//
#include <hip/hip_runtime.h>
#include <cstdint>
#include <cstddef>

#define Bb 8
#define Ss 2048
#define Dd 512

typedef _Float16 half8 __attribute__((ext_vector_type(8)));
typedef _Float16 half4_ __attribute__((ext_vector_type(4)));
typedef _Float16 half2_t __attribute__((ext_vector_type(2)));
typedef float f32x4 __attribute__((ext_vector_type(4)));

static __device__ __forceinline__ void gload_lds16(const void* g, void* l) {
  __builtin_amdgcn_global_load_lds((const __attribute__((address_space(1))) void*)g,
                                   (__attribute__((address_space(3))) void*)l,
                                   16, 0, 0);
}

// ---------------- K0: fused prep, v2 (coalescing-first) ---------------- (unchanged)
__global__ void k0_prep(const float* __restrict__ enc, const float* __restrict__ dec,
                        _Float16* __restrict__ enc16, _Float16* __restrict__ encT,
                        _Float16* __restrict__ dec16) {
  __shared__ _Float16 tb[8][64][8];  // [key>>3][d][key&7], 8 KB
  int bid = blockIdx.x;
  int b = bid & 7, kt = (bid >> 3) & 31, dt = bid >> 8;  // 8*32*8 = 2048
  int key0 = kt * 64, d0 = dt * 64;
  int t = threadIdx.x;

  {
    size_t off = (size_t)bid * 4096 + (size_t)t * 16;
    const float4* p = (const float4*)(dec + off);
    float4 a0 = p[0], a1 = p[1], a2 = p[2], a3 = p[3];
    half8 h0, h1;
    h0[0] = (_Float16)a0.x; h0[1] = (_Float16)a0.y; h0[2] = (_Float16)a0.z; h0[3] = (_Float16)a0.w;
    h0[4] = (_Float16)a1.x; h0[5] = (_Float16)a1.y; h0[6] = (_Float16)a1.z; h0[7] = (_Float16)a1.w;
    h1[0] = (_Float16)a2.x; h1[1] = (_Float16)a2.y; h1[2] = (_Float16)a2.z; h1[3] = (_Float16)a2.w;
    h1[4] = (_Float16)a3.x; h1[5] = (_Float16)a3.y; h1[6] = (_Float16)a3.z; h1[7] = (_Float16)a3.w;
    *(half8*)(dec16 + off) = h0;
    *(half8*)(dec16 + off + 8) = h1;
  }

  const float* src = enc + ((size_t)b * Ss + key0) * Dd + d0;
  _Float16* d16 = enc16 + ((size_t)b * Ss + key0) * Dd + d0;
#pragma unroll
  for (int p = 0; p < 4; ++p) {
    int row = p * 16 + (t >> 4);
    int c = (t & 15) * 4;
    float4 a = *(const float4*)(src + (size_t)row * Dd + c);
    half4_ h;
    h[0] = (_Float16)a.x; h[1] = (_Float16)a.y; h[2] = (_Float16)a.z; h[3] = (_Float16)a.w;
    *(half4_*)(d16 + (size_t)row * Dd + c) = h;
    int K = row >> 3, k = row & 7;
#pragma unroll
    for (int i = 0; i < 4; ++i) tb[K][c + i][k] = h[i];
  }
  __syncthreads();

  _Float16* oT = encT + ((size_t)b * Dd + d0) * Ss + key0;
#pragma unroll
  for (int q = 0; q < 2; ++q) {
    int d = q * 32 + (t >> 3);
    int k8 = (t & 7) * 8;
    half8 v = *(const half8*)&tb[k8 >> 3][d][0];
    *(half8*)(oT + (size_t)d * Ss + k8) = v;
  }
}

// ---------------- K1 v3: 256^2 tile, 8 waves, 4-phase/K-tile counted-vmcnt schedule ----
// T2 (XOR swizzle) + T3/T4 (phased interleave, vmcnt(4) never 0 in steady state) +
// T5 (setprio around MFMA cluster). LDS 128 KB dynamic: [A0|A1|B0|B1] x 16384 halfs.
// Launch hardened: func-attribute opt-in + runtime gate + 2-phase fallback (below).
template<int QM, int QN>
static __device__ __forceinline__ void mfma16(f32x4 (&acc)[8][4],
                                              const half8 (&af)[4][2],
                                              const half8 (&bf)[2][2]) {
#pragma unroll
  for (int ks = 0; ks < 2; ++ks)
#pragma unroll
    for (int mt2 = 0; mt2 < 4; ++mt2)
#pragma unroll
      for (int ntl = 0; ntl < 2; ++ntl)
        acc[QM * 4 + mt2][QN * 2 + ntl] = __builtin_amdgcn_mfma_f32_16x16x32_f16(
            af[mt2][ks], bf[ntl][ks], acc[QM * 4 + mt2][QN * 2 + ntl], 0, 0, 0);
}

#define WAITVM4 do { asm volatile("s_waitcnt vmcnt(4)" ::: "memory"); __builtin_amdgcn_sched_barrier(0); } while (0)
#define WAITVM0 do { asm volatile("s_waitcnt vmcnt(0)" ::: "memory"); __builtin_amdgcn_sched_barrier(0); } while (0)
#define BAR() __builtin_amdgcn_s_barrier()

__launch_bounds__(512, 2)
__global__ void k1_qk(const _Float16* __restrict__ A, const _Float16* __restrict__ Bm,
                      _Float16* __restrict__ S, half2_t* __restrict__ pms) {
  extern __shared__ _Float16 smem[];  // 65536 halfs = 128 KB: A(2x16384) | B(2x16384)
  int bid = blockIdx.x;
  int b = bid & 7;
  int tt = bid >> 3;                  // 0..63
  int tm = tt & 7, tn = tt >> 3;      // 8 x 8 tiles of 256
  int tid = threadIdx.x;
  int w = tid >> 6, L = tid & 63;
  int wm = w >> 2, wn = w & 3;        // 2 x 4 wave grid; per-wave output 128x64
  int g = L >> 4, lm = L & 15;

  const _Float16* Ag = A + ((size_t)b * Ss + (size_t)tm * 256) * Dd;
  const _Float16* Bg = Bm + ((size_t)b * Ss + (size_t)tn * 256) * Dd;

  // --- staging source pointers (pre-swizzled global col, linear LDS dest: m173 pattern) ---
  int sl0 = (w * 2 + 0) * 512 + L * 8;   // linear f16 slot within a 16 KB group region
  int sl1 = (w * 2 + 1) * 512 + L * 8;
  const _Float16* gA[2][2];
  const _Float16* gB[2][2];
#pragma unroll
  for (int j = 0; j < 2; ++j) {
    int sl = j ? sl1 : sl0;
    int lr = sl >> 6;                  // 0..127 local row within group
    int oct = (sl >> 3) & 7;           // LDS octet position
#pragma unroll
    for (int ga = 0; ga < 2; ++ga) {
      int row = (lr >> 6) * 128 + ga * 64 + (lr & 63);
      gA[ga][j] = Ag + (size_t)row * Dd + ((oct ^ (row & 7)) * 8);
    }
#pragma unroll
    for (int qn = 0; qn < 2; ++qn) {
      int row = (lr >> 5) * 64 + qn * 32 + (lr & 31);
      gB[qn][j] = Bg + (size_t)row * Dd + ((oct ^ (row & 7)) * 8);
    }
  }

  f32x4 acc[8][4];
#pragma unroll
  for (int i = 0; i < 8; ++i)
#pragma unroll
    for (int j = 0; j < 4; ++j) acc[i][j] = (f32x4){0.f, 0.f, 0.f, 0.f};

  // --- read-side lane constants ---
  int o80 = ((0 * 4 + g) ^ (lm & 7)) * 8;  // ks=0 octet offset (halfs)
  int o81 = ((1 * 4 + g) ^ (lm & 7)) * 8;  // ks=1
  int aBase = (wm * 64 + lm) * 64;
  int bBase = (wn * 32 + lm) * 64;

  // --- prologue: issue tile 0 groups in steady-state order A0,B0,B1,A1 ---
  gload_lds16(gA[0][0], smem + sl0);
  gload_lds16(gA[0][1], smem + sl1);
  gload_lds16(gB[0][0], smem + 32768 + sl0);
  gload_lds16(gB[0][1], smem + 32768 + sl1);
  gload_lds16(gB[1][0], smem + 32768 + 8192 + sl0);
  gload_lds16(gB[1][1], smem + 32768 + 8192 + sl1);
  gload_lds16(gA[1][0], smem + 8192 + sl0);
  gload_lds16(gA[1][1], smem + 8192 + sl1);
  WAITVM4;   // A-g0, B-g0 landed
  BAR();

  const int NT = Dd / 64;  // 8 K-tiles
#pragma unroll 2
  for (int t = 0; t < NT; ++t) {
    int cb = t & 1, nb = cb ^ 1;
    const _Float16* pAr = smem + cb * 16384 + aBase;
    const _Float16* pBr = smem + 32768 + cb * 16384 + bBase;
    _Float16* lAn = smem + nb * 16384;
    _Float16* lBn = smem + 32768 + nb * 16384;
    int k0n = (t + 1) * 64;
    bool pre = (t < NT - 1);
    half8 af[4][2], bf[2][2];

    // ---- phase 0: (qm=0, qn=0) ----
#pragma unroll
    for (int mt2 = 0; mt2 < 4; ++mt2) {
      af[mt2][0] = *(const half8*)(pAr + mt2 * 1024 + o80);
      af[mt2][1] = *(const half8*)(pAr + mt2 * 1024 + o81);
    }
#pragma unroll
    for (int ntl = 0; ntl < 2; ++ntl) {
      bf[ntl][0] = *(const half8*)(pBr + ntl * 1024 + o80);
      bf[ntl][1] = *(const half8*)(pBr + ntl * 1024 + o81);
    }
    if (pre) { gload_lds16(gA[0][0] + k0n, lAn + sl0); gload_lds16(gA[0][1] + k0n, lAn + sl1); }
    BAR();
    __builtin_amdgcn_s_setprio(1);
    mfma16<0, 0>(acc, af, bf);
    __builtin_amdgcn_s_setprio(0);
    if (pre) WAITVM4;  // B-g1(t) landed
    BAR();

    // ---- phase 1: (qm=0, qn=1) — af held ----
#pragma unroll
    for (int ntl = 0; ntl < 2; ++ntl) {
      bf[ntl][0] = *(const half8*)(pBr + 8192 + ntl * 1024 + o80);
      bf[ntl][1] = *(const half8*)(pBr + 8192 + ntl * 1024 + o81);
    }
    if (pre) { gload_lds16(gB[0][0] + k0n, lBn + sl0); gload_lds16(gB[0][1] + k0n, lBn + sl1); }
    BAR();
    __builtin_amdgcn_s_setprio(1);
    mfma16<0, 1>(acc, af, bf);
    __builtin_amdgcn_s_setprio(0);
    if (pre) WAITVM4;  // A-g1(t) landed
    BAR();

    // ---- phase 2: (qm=1, qn=1) — bf (qn=1) held ----
#pragma unroll
    for (int mt2 = 0; mt2 < 4; ++mt2) {
      af[mt2][0] = *(const half8*)(pAr + 8192 + mt2 * 1024 + o80);
      af[mt2][1] = *(const half8*)(pAr + 8192 + mt2 * 1024 + o81);
    }
    if (pre) { gload_lds16(gB[1][0] + k0n, lBn + 8192 + sl0); gload_lds16(gB[1][1] + k0n, lBn + 8192 + sl1); }
    BAR();
    __builtin_amdgcn_s_setprio(1);
    mfma16<1, 1>(acc, af, bf);
    __builtin_amdgcn_s_setprio(0);
    BAR();  // no wait: phase 3 re-reads B-g0 (long landed)

    // ---- phase 3: (qm=1, qn=0) — af held ----
#pragma unroll
    for (int ntl = 0; ntl < 2; ++ntl) {
      bf[ntl][0] = *(const half8*)(pBr + ntl * 1024 + o80);
      bf[ntl][1] = *(const half8*)(pBr + ntl * 1024 + o81);
    }
    if (pre) { gload_lds16(gA[1][0] + k0n, lAn + 8192 + sl0); gload_lds16(gA[1][1] + k0n, lAn + 8192 + sl1); }
    BAR();
    __builtin_amdgcn_s_setprio(1);
    mfma16<1, 0>(acc, af, bf);
    __builtin_amdgcn_s_setprio(0);
    if (t < NT - 2) { WAITVM4; }        // A-g0(t+1), B-g0(t+1) landed
    else if (t == NT - 2) { WAITVM0; }  // tail: drain once; last tile waitless
    BAR();
  }

  // ---- epilogue: per (row, 64-col chunk) max + exp + sum; e = exp(s - m_c) as f16 ----
  size_t rowbase = (size_t)b * Ss;
#pragma unroll
  for (int mt = 0; mt < 8; ++mt) {
#pragma unroll
    for (int r = 0; r < 4; ++r) {
      int row_g = tm * 256 + wm * 128 + mt * 16 + g * 4 + r;  // == wm*128+(mt>>2)*64+(mt&3)*16+...
      _Float16* Srow = S + (rowbase + row_g) * Ss + (size_t)tn * 256 + wn * 64 + lm;
      float rm = -1e30f;
#pragma unroll
      for (int nt = 0; nt < 4; ++nt) rm = fmaxf(rm, acc[mt][nt][r]);
      rm = fmaxf(rm, __shfl_xor(rm, 1));
      rm = fmaxf(rm, __shfl_xor(rm, 2));
      rm = fmaxf(rm, __shfl_xor(rm, 4));
      rm = fmaxf(rm, __shfl_xor(rm, 8));
      _Float16 mh = (_Float16)rm;   // f16-rounded chunk max; SAME value re-derived in k3 prologue
      float mf = (float)mh;
      float sum = 0.f;
#pragma unroll
      for (int nt = 0; nt < 4; ++nt) {
        float e = __expf(acc[mt][nt][r] - mf);
        Srow[nt * 16] = (_Float16)e;
        sum += e;
      }
      sum += __shfl_xor(sum, 1);
      sum += __shfl_xor(sum, 2);
      sum += __shfl_xor(sum, 4);
      sum += __shfl_xor(sum, 8);
      if (lm == 0) {
        half2_t st; st.x = mh; st.y = (_Float16)sum;
        pms[(rowbase + row_g) * 32 + tn * 4 + wn] = st;
      }
    }
  }
}

// ---------------- K1 fallback: round-0 verified 2-phase 128x128 (64 KB-safe) ----------
__launch_bounds__(256, 2)
__global__ void k1_qk_fb(const _Float16* __restrict__ A, const _Float16* __restrict__ Bm,
                         _Float16* __restrict__ S, half2_t* __restrict__ pms) {
  __shared__ __align__(16) _Float16 lA[128 * 64];
  __shared__ __align__(16) _Float16 lB[128 * 64];
  int bid = blockIdx.x;
  int b = bid & 7;
  int t = bid >> 3;
  int tm = t & 15, tn = t >> 4;
  int tid = threadIdx.x;
  int w = tid >> 6, L = tid & 63;
  int wm = w & 1, wn = w >> 1;

  const _Float16* Ag = A + ((size_t)b * Ss + (size_t)tm * 128) * Dd;
  const _Float16* Bg = Bm + ((size_t)b * Ss + (size_t)tn * 128) * Dd;

  int rowS[4], colS[4], ldsOff[4];
#pragma unroll
  for (int i = 0; i < 4; ++i) {
    int se = (w * 4 + i) * 512 + L * 8;
    int row = se >> 6;
    int blk = (se >> 3) & 7;
    rowS[i] = row;
    colS[i] = (blk ^ (row & 7)) << 3;
    ldsOff[i] = se;
  }

  f32x4 acc[4][4];
#pragma unroll
  for (int mt = 0; mt < 4; ++mt)
#pragma unroll
    for (int nt = 0; nt < 4; ++nt) acc[mt][nt] = (f32x4){0.f, 0.f, 0.f, 0.f};

  int g = L >> 4, lm = L & 15;

  for (int k0 = 0; k0 < Dd; k0 += 64) {
    __syncthreads();
#pragma unroll
    for (int i = 0; i < 4; ++i) {
      gload_lds16(Ag + (size_t)rowS[i] * Dd + k0 + colS[i], lA + ldsOff[i]);
      gload_lds16(Bg + (size_t)rowS[i] * Dd + k0 + colS[i], lB + ldsOff[i]);
    }
    __syncthreads();
#pragma unroll
    for (int ds = 0; ds < 64; ds += 32) {
      half8 af[4], bf[4];
#pragma unroll
      for (int mt = 0; mt < 4; ++mt) {
        int row = wm * 64 + mt * 16 + lm;
        int blk = ((ds >> 3) + g) ^ (row & 7);
        af[mt] = *(const half8*)(lA + row * 64 + blk * 8);
      }
#pragma unroll
      for (int nt = 0; nt < 4; ++nt) {
        int row = wn * 64 + nt * 16 + lm;
        int blk = ((ds >> 3) + g) ^ (row & 7);
        bf[nt] = *(const half8*)(lB + row * 64 + blk * 8);
      }
#pragma unroll
      for (int mt = 0; mt < 4; ++mt)
#pragma unroll
        for (int nt = 0; nt < 4; ++nt)
          acc[mt][nt] = __builtin_amdgcn_mfma_f32_16x16x32_f16(af[mt], bf[nt], acc[mt][nt], 0, 0, 0);
    }
  }

  size_t rowbase = (size_t)b * Ss;
#pragma unroll
  for (int mt = 0; mt < 4; ++mt) {
#pragma unroll
    for (int r = 0; r < 4; ++r) {
      int row_g = tm * 128 + wm * 64 + mt * 16 + g * 4 + r;
      _Float16* Srow = S + (rowbase + row_g) * Ss + (size_t)tn * 128 + wn * 64 + lm;
      float rm = -1e30f;
#pragma unroll
      for (int nt = 0; nt < 4; ++nt) rm = fmaxf(rm, acc[mt][nt][r]);
      rm = fmaxf(rm, __shfl_xor(rm, 1));
      rm = fmaxf(rm, __shfl_xor(rm, 2));
      rm = fmaxf(rm, __shfl_xor(rm, 4));
      rm = fmaxf(rm, __shfl_xor(rm, 8));
      _Float16 mh = (_Float16)rm;
      float mf = (float)mh;
      float sum = 0.f;
#pragma unroll
      for (int nt = 0; nt < 4; ++nt) {
        float e = __expf(acc[mt][nt][r] - mf);
        Srow[nt * 16] = (_Float16)e;
        sum += e;
      }
      sum += __shfl_xor(sum, 1);
      sum += __shfl_xor(sum, 2);
      sum += __shfl_xor(sum, 4);
      sum += __shfl_xor(sum, 8);
      if (lm == 0) {
        half2_t st; st.x = mh; st.y = (_Float16)sum;
        pms[(rowbase + row_g) * 32 + tn * 2 + wn] = st;
      }
    }
  }
}

// ---------------- K3: C = (e .* factor) @ V  — 128x64 tiles (unchanged this round) -----
__launch_bounds__(256, 4)
__global__ void k3_pv(const _Float16* __restrict__ P, const _Float16* __restrict__ Vt,
                      const half2_t* __restrict__ pms, float* __restrict__ C) {
  __shared__ __align__(16) _Float16 lA[128 * 64];
  __shared__ __align__(16) _Float16 lB[64 * 64];
  __shared__ float fctL[32 * 128];  // [chunk][row] 16 KB
  int bid = blockIdx.x;
  int b = bid & 7;
  int t = bid >> 3;
  int tm = t & 15, tn = t >> 4;
  int tid = threadIdx.x;
  int w = tid >> 6, L = tid & 63;
  int wm = w & 1, wn = w >> 1;

  if (tid < 128) {
    const half2_t* pr = pms + ((size_t)b * Ss + (size_t)tm * 128 + tid) * 32;
    float mc[32], sc[32];
#pragma unroll
    for (int c = 0; c < 32; ++c) { half2_t v = pr[c]; mc[c] = (float)v.x; sc[c] = (float)v.y; }
    float m = mc[0];
#pragma unroll
    for (int c = 1; c < 32; ++c) m = fmaxf(m, mc[c]);
    float tot = 0.f;
    float ef[32];
#pragma unroll
    for (int c = 0; c < 32; ++c) { ef[c] = __expf(mc[c] - m); tot += sc[c] * ef[c]; }
    float rinv = 1.0f / tot;
#pragma unroll
    for (int c = 0; c < 32; ++c) fctL[c * 128 + tid] = ef[c] * rinv;
  }

  const _Float16* Ag = P + ((size_t)b * Ss + (size_t)tm * 128) * Ss;
  const _Float16* Bg = Vt + ((size_t)b * Dd + (size_t)tn * 64) * Ss;

  int rowA[4], colA[4], offA[4];
#pragma unroll
  for (int i = 0; i < 4; ++i) {
    int se = (w * 4 + i) * 512 + L * 8;
    int row = se >> 6;
    int blk = (se >> 3) & 7;
    rowA[i] = row;
    colA[i] = (blk ^ (row & 7)) << 3;
    offA[i] = se;
  }
  int rowB[2], colB[2], offB[2];
#pragma unroll
  for (int i = 0; i < 2; ++i) {
    int se = (w * 2 + i) * 512 + L * 8;
    int row = se >> 6;
    int blk = (se >> 3) & 7;
    rowB[i] = row;
    colB[i] = (blk ^ (row & 7)) << 3;
    offB[i] = se;
  }

  f32x4 acc[4][2];
#pragma unroll
  for (int mt = 0; mt < 4; ++mt)
#pragma unroll
    for (int nt = 0; nt < 2; ++nt) acc[mt][nt] = (f32x4){0.f, 0.f, 0.f, 0.f};

  int g = L >> 4, lm = L & 15;

  for (int k0 = 0; k0 < Ss; k0 += 64) {
    __syncthreads();
#pragma unroll
    for (int i = 0; i < 4; ++i)
      gload_lds16(Ag + (size_t)rowA[i] * Ss + k0 + colA[i], lA + offA[i]);
#pragma unroll
    for (int i = 0; i < 2; ++i)
      gload_lds16(Bg + (size_t)rowB[i] * Ss + k0 + colB[i], lB + offB[i]);
    __syncthreads();
    _Float16 fh[4];
#pragma unroll
    for (int mt = 0; mt < 4; ++mt)
      fh[mt] = (_Float16)fctL[(k0 >> 6) * 128 + wm * 64 + mt * 16 + lm];
#pragma unroll
    for (int ds = 0; ds < 64; ds += 32) {
      half8 af[4], bf[2];
#pragma unroll
      for (int mt = 0; mt < 4; ++mt) {
        int row = wm * 64 + mt * 16 + lm;
        int blk = ((ds >> 3) + g) ^ (row & 7);
        af[mt] = *(const half8*)(lA + row * 64 + blk * 8);
#pragma unroll
        for (int j = 0; j < 8; ++j) af[mt][j] *= fh[mt];
      }
#pragma unroll
      for (int nt = 0; nt < 2; ++nt) {
        int row = wn * 32 + nt * 16 + lm;
        int blk = ((ds >> 3) + g) ^ (row & 7);
        bf[nt] = *(const half8*)(lB + row * 64 + blk * 8);
      }
#pragma unroll
      for (int mt = 0; mt < 4; ++mt)
#pragma unroll
        for (int nt = 0; nt < 2; ++nt)
          acc[mt][nt] = __builtin_amdgcn_mfma_f32_16x16x32_f16(af[mt], bf[nt], acc[mt][nt], 0, 0, 0);
    }
  }

#pragma unroll
  for (int mt = 0; mt < 4; ++mt) {
#pragma unroll
    for (int r = 0; r < 4; ++r) {
      int row_g = tm * 128 + wm * 64 + mt * 16 + g * 4 + r;
      float* Crow = C + ((size_t)b * Ss + row_g) * Dd + (size_t)tn * 64 + wn * 32 + lm;
#pragma unroll
      for (int nt = 0; nt < 2; ++nt) Crow[nt * 16] = acc[mt][nt][r];
    }
  }
}

extern "C" void kernel_launch(void* const* d_in, const int* in_sizes, int n_in,
                              void* d_out, int out_size, void* d_ws, size_t ws_size,
                              hipStream_t stream) {
  const float* enc = (const float*)d_in[0];
  const float* dec = (const float*)d_in[1];
  float* out = (float*)d_out;

  const size_t nElem = (size_t)Bb * Ss * Dd;  // 8388608
  const size_t nS = (size_t)Bb * Ss * Ss;     // 33554432

  _Float16* dec16 = (_Float16*)d_ws;
  _Float16* enc16 = dec16 + nElem;
  _Float16* encT = enc16 + nElem;
  _Float16* Sp = encT + nElem;
  half2_t* pms = (half2_t*)(Sp + nS);

  size_t need = nElem * 2 * 3 + nS * 2 + (size_t)Bb * Ss * 32 * 4;
  if (ws_size < need) return;

  // One-time gate: can k1_qk launch with 128 KB dynamic LDS? (host-side queries only —
  // graph-capture safe). If not provably yes, use the 64 KB-safe 2-phase fallback
  // instead of risking a failed launch inside capture.
  static int g_k1_big = -1;
  if (g_k1_big < 0) {
    int ok = 0;
    (void)hipFuncSetAttribute(reinterpret_cast<const void*>(&k1_qk),
                              hipFuncAttributeMaxDynamicSharedMemorySize, 131072);
    hipFuncAttributes fa;
    if (hipFuncGetAttributes(&fa, reinterpret_cast<const void*>(&k1_qk)) == hipSuccess &&
        fa.maxDynamicSharedSizeBytes >= 131072) ok = 1;
    if (!ok) {
      int dev = 0, maxShm = 0;
      (void)hipGetDevice(&dev);
      if (hipDeviceGetAttribute(&maxShm, hipDeviceAttributeMaxSharedMemoryPerBlock, dev) ==
              hipSuccess && maxShm >= 131072) ok = 1;
    }
    g_k1_big = ok;
  }

  k0_prep<<<2048, 256, 0, stream>>>(enc, dec, enc16, encT, dec16);
  if (g_k1_big)
    k1_qk<<<512, 512, 131072, stream>>>(dec16, enc16, Sp, pms);
  else
    k1_qk_fb<<<2048, 256, 0, stream>>>(dec16, enc16, Sp, pms);
  k3_pv<<<1024, 256, 0, stream>>>(Sp, encT, pms, out);
}

// Round 3
// 201.067 us; speedup vs baseline: 1.0242x; 1.0242x over previous
//
#include <hip/hip_runtime.h>
#include <cstdint>
#include <cstddef>

#define Bb 8
#define Ss 2048
#define Dd 512

typedef _Float16 half8 __attribute__((ext_vector_type(8)));
typedef _Float16 half4_ __attribute__((ext_vector_type(4)));
typedef _Float16 half2_t __attribute__((ext_vector_type(2)));
typedef float f32x4 __attribute__((ext_vector_type(4)));

static __device__ __forceinline__ void gload_lds16(const void* g, void* l) {
  __builtin_amdgcn_global_load_lds((const __attribute__((address_space(1))) void*)g,
                                   (__attribute__((address_space(3))) void*)l,
                                   16, 0, 0);
}

// ---------------- K0: fused prep, v2 (coalescing-first) ---------------- (unchanged)
__global__ void k0_prep(const float* __restrict__ enc, const float* __restrict__ dec,
                        _Float16* __restrict__ enc16, _Float16* __restrict__ encT,
                        _Float16* __restrict__ dec16) {
  __shared__ _Float16 tb[8][64][8];  // [key>>3][d][key&7], 8 KB
  int bid = blockIdx.x;
  int b = bid & 7, kt = (bid >> 3) & 31, dt = bid >> 8;  // 8*32*8 = 2048
  int key0 = kt * 64, d0 = dt * 64;
  int t = threadIdx.x;

  {
    size_t off = (size_t)bid * 4096 + (size_t)t * 16;
    const float4* p = (const float4*)(dec + off);
    float4 a0 = p[0], a1 = p[1], a2 = p[2], a3 = p[3];
    half8 h0, h1;
    h0[0] = (_Float16)a0.x; h0[1] = (_Float16)a0.y; h0[2] = (_Float16)a0.z; h0[3] = (_Float16)a0.w;
    h0[4] = (_Float16)a1.x; h0[5] = (_Float16)a1.y; h0[6] = (_Float16)a1.z; h0[7] = (_Float16)a1.w;
    h1[0] = (_Float16)a2.x; h1[1] = (_Float16)a2.y; h1[2] = (_Float16)a2.z; h1[3] = (_Float16)a2.w;
    h1[4] = (_Float16)a3.x; h1[5] = (_Float16)a3.y; h1[6] = (_Float16)a3.z; h1[7] = (_Float16)a3.w;
    *(half8*)(dec16 + off) = h0;
    *(half8*)(dec16 + off + 8) = h1;
  }

  const float* src = enc + ((size_t)b * Ss + key0) * Dd + d0;
  _Float16* d16 = enc16 + ((size_t)b * Ss + key0) * Dd + d0;
#pragma unroll
  for (int p = 0; p < 4; ++p) {
    int row = p * 16 + (t >> 4);
    int c = (t & 15) * 4;
    float4 a = *(const float4*)(src + (size_t)row * Dd + c);
    half4_ h;
    h[0] = (_Float16)a.x; h[1] = (_Float16)a.y; h[2] = (_Float16)a.z; h[3] = (_Float16)a.w;
    *(half4_*)(d16 + (size_t)row * Dd + c) = h;
    int K = row >> 3, k = row & 7;
#pragma unroll
    for (int i = 0; i < 4; ++i) tb[K][c + i][k] = h[i];
  }
  __syncthreads();

  _Float16* oT = encT + ((size_t)b * Dd + d0) * Ss + key0;
#pragma unroll
  for (int q = 0; q < 2; ++q) {
    int d = q * 32 + (t >> 3);
    int k8 = (t & 7) * 8;
    half8 v = *(const half8*)&tb[k8 >> 3][d][0];
    *(half8*)(oT + (size_t)d * Ss + k8) = v;
  }
}

// ---------------- K1 v4: 256^2 tile, 8 waves, 4-phase/K-tile, DEEP counted-vmcnt ------
// Round-2 post-mortem: every wait targeted loads only 2 phases old -> pipeline shallower
// than the 2-phase baseline. v4 keeps identical index math / reads / epilogue (verified
// in round 2) and changes ONLY issue points + wait values so each wait touches loads
// >=3 phases old (m201 depth: 8 loads / 4 half-tiles in flight, invariant 4 outstanding
// at each tile boundary):
//   p0: issue A0+B0(t+1) -> end-p0 vmcnt(6)  [covers B1(t), issued p1(t-1)]
//   p1: issue B1(t+1)    -> end-p1 vmcnt(6)  [covers A1(t), issued p2(t-1)]
//   p2: issue A1(t+1)    -> no wait
//   p3: no issue         -> end-p3 vmcnt(4)  [covers A0B0(t+1), issued p0(t)]
// Tail t=NT-1: vmcnt(2) at p0, vmcnt(0) at p1.
template<int QM, int QN>
static __device__ __forceinline__ void mfma16(f32x4 (&acc)[8][4],
                                              const half8 (&af)[4][2],
                                              const half8 (&bf)[2][2]) {
#pragma unroll
  for (int ks = 0; ks < 2; ++ks)
#pragma unroll
    for (int mt2 = 0; mt2 < 4; ++mt2)
#pragma unroll
      for (int ntl = 0; ntl < 2; ++ntl)
        acc[QM * 4 + mt2][QN * 2 + ntl] = __builtin_amdgcn_mfma_f32_16x16x32_f16(
            af[mt2][ks], bf[ntl][ks], acc[QM * 4 + mt2][QN * 2 + ntl], 0, 0, 0);
}

#define WAITVM(N) do { asm volatile("s_waitcnt vmcnt(" #N ")" ::: "memory"); __builtin_amdgcn_sched_barrier(0); } while (0)
#define BAR() __builtin_amdgcn_s_barrier()

__launch_bounds__(512, 2)
__global__ void k1_qk(const _Float16* __restrict__ A, const _Float16* __restrict__ Bm,
                      _Float16* __restrict__ S, half2_t* __restrict__ pms) {
  extern __shared__ _Float16 smem[];  // 65536 halfs = 128 KB: A(2x16384) | B(2x16384)
  int bid = blockIdx.x;
  int b = bid & 7;
  int tt = bid >> 3;                  // 0..63
  int tm = tt & 7, tn = tt >> 3;      // 8 x 8 tiles of 256
  int tid = threadIdx.x;
  int w = tid >> 6, L = tid & 63;
  int wm = w >> 2, wn = w & 3;        // 2 x 4 wave grid; per-wave output 128x64
  int g = L >> 4, lm = L & 15;

  const _Float16* Ag = A + ((size_t)b * Ss + (size_t)tm * 256) * Dd;
  const _Float16* Bg = Bm + ((size_t)b * Ss + (size_t)tn * 256) * Dd;

  // --- staging source pointers (pre-swizzled global col, linear LDS dest: m173 pattern) ---
  int sl0 = (w * 2 + 0) * 512 + L * 8;   // linear f16 slot within a 16 KB group region
  int sl1 = (w * 2 + 1) * 512 + L * 8;
  const _Float16* gA[2][2];
  const _Float16* gB[2][2];
#pragma unroll
  for (int j = 0; j < 2; ++j) {
    int sl = j ? sl1 : sl0;
    int lr = sl >> 6;                  // 0..127 local row within group
    int oct = (sl >> 3) & 7;           // LDS octet position
#pragma unroll
    for (int ga = 0; ga < 2; ++ga) {
      int row = (lr >> 6) * 128 + ga * 64 + (lr & 63);
      gA[ga][j] = Ag + (size_t)row * Dd + ((oct ^ (row & 7)) * 8);
    }
#pragma unroll
    for (int qn = 0; qn < 2; ++qn) {
      int row = (lr >> 5) * 64 + qn * 32 + (lr & 31);
      gB[qn][j] = Bg + (size_t)row * Dd + ((oct ^ (row & 7)) * 8);
    }
  }

  f32x4 acc[8][4];
#pragma unroll
  for (int i = 0; i < 8; ++i)
#pragma unroll
    for (int j = 0; j < 4; ++j) acc[i][j] = (f32x4){0.f, 0.f, 0.f, 0.f};

  // --- read-side lane constants ---
  int o80 = ((0 * 4 + g) ^ (lm & 7)) * 8;  // ks=0 octet offset (halfs)
  int o81 = ((1 * 4 + g) ^ (lm & 7)) * 8;  // ks=1
  int aBase = (wm * 64 + lm) * 64;
  int bBase = (wn * 32 + lm) * 64;

  // --- prologue: issue tile 0 groups A0,B0,B1,A1; wait A0B0 only ---
  gload_lds16(gA[0][0], smem + sl0);
  gload_lds16(gA[0][1], smem + sl1);
  gload_lds16(gB[0][0], smem + 32768 + sl0);
  gload_lds16(gB[0][1], smem + 32768 + sl1);
  gload_lds16(gB[1][0], smem + 32768 + 8192 + sl0);
  gload_lds16(gB[1][1], smem + 32768 + 8192 + sl1);
  gload_lds16(gA[1][0], smem + 8192 + sl0);
  gload_lds16(gA[1][1], smem + 8192 + sl1);
  WAITVM(4);   // A-g0, B-g0 landed; B1,A1 (4 instr) stay in flight
  BAR();

  const int NT = Dd / 64;  // 8 K-tiles
#pragma unroll 2
  for (int t = 0; t < NT; ++t) {
    int cb = t & 1, nb = cb ^ 1;
    const _Float16* pAr = smem + cb * 16384 + aBase;
    const _Float16* pBr = smem + 32768 + cb * 16384 + bBase;
    _Float16* lAn = smem + nb * 16384;
    _Float16* lBn = smem + 32768 + nb * 16384;
    int k0n = (t + 1) * 64;
    bool pre = (t < NT - 1);
    half8 af[4][2], bf[2][2];

    // ---- phase 0: (qm=0, qn=0); issue A0+B0(t+1) ----
#pragma unroll
    for (int mt2 = 0; mt2 < 4; ++mt2) {
      af[mt2][0] = *(const half8*)(pAr + mt2 * 1024 + o80);
      af[mt2][1] = *(const half8*)(pAr + mt2 * 1024 + o81);
    }
#pragma unroll
    for (int ntl = 0; ntl < 2; ++ntl) {
      bf[ntl][0] = *(const half8*)(pBr + ntl * 1024 + o80);
      bf[ntl][1] = *(const half8*)(pBr + ntl * 1024 + o81);
    }
    if (pre) {
      gload_lds16(gA[0][0] + k0n, lAn + sl0); gload_lds16(gA[0][1] + k0n, lAn + sl1);
      gload_lds16(gB[0][0] + k0n, lBn + sl0); gload_lds16(gB[0][1] + k0n, lBn + sl1);
    }
    BAR();
    __builtin_amdgcn_s_setprio(1);
    mfma16<0, 0>(acc, af, bf);
    __builtin_amdgcn_s_setprio(0);
    if (pre) WAITVM(6); else WAITVM(2);   // B-g1(t) landed (issued p1(t-1))
    BAR();

    // ---- phase 1: (qm=0, qn=1) — af held; issue B1(t+1) ----
#pragma unroll
    for (int ntl = 0; ntl < 2; ++ntl) {
      bf[ntl][0] = *(const half8*)(pBr + 8192 + ntl * 1024 + o80);
      bf[ntl][1] = *(const half8*)(pBr + 8192 + ntl * 1024 + o81);
    }
    if (pre) { gload_lds16(gB[1][0] + k0n, lBn + 8192 + sl0); gload_lds16(gB[1][1] + k0n, lBn + 8192 + sl1); }
    BAR();
    __builtin_amdgcn_s_setprio(1);
    mfma16<0, 1>(acc, af, bf);
    __builtin_amdgcn_s_setprio(0);
    if (pre) WAITVM(6); else WAITVM(0);   // A-g1(t) landed (issued p2(t-1))
    BAR();

    // ---- phase 2: (qm=1, qn=1) — bf (qn=1) held; issue A1(t+1) ----
#pragma unroll
    for (int mt2 = 0; mt2 < 4; ++mt2) {
      af[mt2][0] = *(const half8*)(pAr + 8192 + mt2 * 1024 + o80);
      af[mt2][1] = *(const half8*)(pAr + 8192 + mt2 * 1024 + o81);
    }
    if (pre) { gload_lds16(gA[1][0] + k0n, lAn + 8192 + sl0); gload_lds16(gA[1][1] + k0n, lAn + 8192 + sl1); }
    BAR();
    __builtin_amdgcn_s_setprio(1);
    mfma16<1, 1>(acc, af, bf);
    __builtin_amdgcn_s_setprio(0);
    BAR();  // no wait: phase 3 re-reads B-g0 (long landed)

    // ---- phase 3: (qm=1, qn=0) — af held; re-read B0; no issue ----
#pragma unroll
    for (int ntl = 0; ntl < 2; ++ntl) {
      bf[ntl][0] = *(const half8*)(pBr + ntl * 1024 + o80);
      bf[ntl][1] = *(const half8*)(pBr + ntl * 1024 + o81);
    }
    BAR();
    __builtin_amdgcn_s_setprio(1);
    mfma16<1, 0>(acc, af, bf);
    __builtin_amdgcn_s_setprio(0);
    if (pre) WAITVM(4);   // A0B0(t+1) landed (issued p0(t)); B1,A1(t+1) stay in flight
    BAR();
  }

  // ---- epilogue: per (row, 64-col chunk) max + exp + sum; e = exp(s - m_c) as f16 ----
  size_t rowbase = (size_t)b * Ss;
#pragma unroll
  for (int mt = 0; mt < 8; ++mt) {
#pragma unroll
    for (int r = 0; r < 4; ++r) {
      int row_g = tm * 256 + wm * 128 + mt * 16 + g * 4 + r;
      _Float16* Srow = S + (rowbase + row_g) * Ss + (size_t)tn * 256 + wn * 64 + lm;
      float rm = -1e30f;
#pragma unroll
      for (int nt = 0; nt < 4; ++nt) rm = fmaxf(rm, acc[mt][nt][r]);
      rm = fmaxf(rm, __shfl_xor(rm, 1));
      rm = fmaxf(rm, __shfl_xor(rm, 2));
      rm = fmaxf(rm, __shfl_xor(rm, 4));
      rm = fmaxf(rm, __shfl_xor(rm, 8));
      _Float16 mh = (_Float16)rm;   // f16-rounded chunk max; SAME value re-derived in k3 prologue
      float mf = (float)mh;
      float sum = 0.f;
#pragma unroll
      for (int nt = 0; nt < 4; ++nt) {
        float e = __expf(acc[mt][nt][r] - mf);
        Srow[nt * 16] = (_Float16)e;
        sum += e;
      }
      sum += __shfl_xor(sum, 1);
      sum += __shfl_xor(sum, 2);
      sum += __shfl_xor(sum, 4);
      sum += __shfl_xor(sum, 8);
      if (lm == 0) {
        half2_t st; st.x = mh; st.y = (_Float16)sum;
        pms[(rowbase + row_g) * 32 + tn * 4 + wn] = st;
      }
    }
  }
}

// ---------------- K1 fallback: round-0 verified 2-phase 128x128 (64 KB-safe) ----------
__launch_bounds__(256, 2)
__global__ void k1_qk_fb(const _Float16* __restrict__ A, const _Float16* __restrict__ Bm,
                         _Float16* __restrict__ S, half2_t* __restrict__ pms) {
  __shared__ __align__(16) _Float16 lA[128 * 64];
  __shared__ __align__(16) _Float16 lB[128 * 64];
  int bid = blockIdx.x;
  int b = bid & 7;
  int t = bid >> 3;
  int tm = t & 15, tn = t >> 4;
  int tid = threadIdx.x;
  int w = tid >> 6, L = tid & 63;
  int wm = w & 1, wn = w >> 1;

  const _Float16* Ag = A + ((size_t)b * Ss + (size_t)tm * 128) * Dd;
  const _Float16* Bg = Bm + ((size_t)b * Ss + (size_t)tn * 128) * Dd;

  int rowS[4], colS[4], ldsOff[4];
#pragma unroll
  for (int i = 0; i < 4; ++i) {
    int se = (w * 4 + i) * 512 + L * 8;
    int row = se >> 6;
    int blk = (se >> 3) & 7;
    rowS[i] = row;
    colS[i] = (blk ^ (row & 7)) << 3;
    ldsOff[i] = se;
  }

  f32x4 acc[4][4];
#pragma unroll
  for (int mt = 0; mt < 4; ++mt)
#pragma unroll
    for (int nt = 0; nt < 4; ++nt) acc[mt][nt] = (f32x4){0.f, 0.f, 0.f, 0.f};

  int g = L >> 4, lm = L & 15;

  for (int k0 = 0; k0 < Dd; k0 += 64) {
    __syncthreads();
#pragma unroll
    for (int i = 0; i < 4; ++i) {
      gload_lds16(Ag + (size_t)rowS[i] * Dd + k0 + colS[i], lA + ldsOff[i]);
      gload_lds16(Bg + (size_t)rowS[i] * Dd + k0 + colS[i], lB + ldsOff[i]);
    }
    __syncthreads();
#pragma unroll
    for (int ds = 0; ds < 64; ds += 32) {
      half8 af[4], bf[4];
#pragma unroll
      for (int mt = 0; mt < 4; ++mt) {
        int row = wm * 64 + mt * 16 + lm;
        int blk = ((ds >> 3) + g) ^ (row & 7);
        af[mt] = *(const half8*)(lA + row * 64 + blk * 8);
      }
#pragma unroll
      for (int nt = 0; nt < 4; ++nt) {
        int row = wn * 64 + nt * 16 + lm;
        int blk = ((ds >> 3) + g) ^ (row & 7);
        bf[nt] = *(const half8*)(lB + row * 64 + blk * 8);
      }
#pragma unroll
      for (int mt = 0; mt < 4; ++mt)
#pragma unroll
        for (int nt = 0; nt < 4; ++nt)
          acc[mt][nt] = __builtin_amdgcn_mfma_f32_16x16x32_f16(af[mt], bf[nt], acc[mt][nt], 0, 0, 0);
    }
  }

  size_t rowbase = (size_t)b * Ss;
#pragma unroll
  for (int mt = 0; mt < 4; ++mt) {
#pragma unroll
    for (int r = 0; r < 4; ++r) {
      int row_g = tm * 128 + wm * 64 + mt * 16 + g * 4 + r;
      _Float16* Srow = S + (rowbase + row_g) * Ss + (size_t)tn * 128 + wn * 64 + lm;
      float rm = -1e30f;
#pragma unroll
      for (int nt = 0; nt < 4; ++nt) rm = fmaxf(rm, acc[mt][nt][r]);
      rm = fmaxf(rm, __shfl_xor(rm, 1));
      rm = fmaxf(rm, __shfl_xor(rm, 2));
      rm = fmaxf(rm, __shfl_xor(rm, 4));
      rm = fmaxf(rm, __shfl_xor(rm, 8));
      _Float16 mh = (_Float16)rm;
      float mf = (float)mh;
      float sum = 0.f;
#pragma unroll
      for (int nt = 0; nt < 4; ++nt) {
        float e = __expf(acc[mt][nt][r] - mf);
        Srow[nt * 16] = (_Float16)e;
        sum += e;
      }
      sum += __shfl_xor(sum, 1);
      sum += __shfl_xor(sum, 2);
      sum += __shfl_xor(sum, 4);
      sum += __shfl_xor(sum, 8);
      if (lm == 0) {
        half2_t st; st.x = mh; st.y = (_Float16)sum;
        pms[(rowbase + row_g) * 32 + tn * 2 + wn] = st;
      }
    }
  }
}

// ---------------- K3: C = (e .* factor) @ V  — 128x64 tiles (unchanged this round) -----
__launch_bounds__(256, 4)
__global__ void k3_pv(const _Float16* __restrict__ P, const _Float16* __restrict__ Vt,
                      const half2_t* __restrict__ pms, float* __restrict__ C) {
  __shared__ __align__(16) _Float16 lA[128 * 64];
  __shared__ __align__(16) _Float16 lB[64 * 64];
  __shared__ float fctL[32 * 128];  // [chunk][row] 16 KB
  int bid = blockIdx.x;
  int b = bid & 7;
  int t = bid >> 3;
  int tm = t & 15, tn = t >> 4;
  int tid = threadIdx.x;
  int w = tid >> 6, L = tid & 63;
  int wm = w & 1, wn = w >> 1;

  if (tid < 128) {
    const half2_t* pr = pms + ((size_t)b * Ss + (size_t)tm * 128 + tid) * 32;
    float mc[32], sc[32];
#pragma unroll
    for (int c = 0; c < 32; ++c) { half2_t v = pr[c]; mc[c] = (float)v.x; sc[c] = (float)v.y; }
    float m = mc[0];
#pragma unroll
    for (int c = 1; c < 32; ++c) m = fmaxf(m, mc[c]);
    float tot = 0.f;
    float ef[32];
#pragma unroll
    for (int c = 0; c < 32; ++c) { ef[c] = __expf(mc[c] - m); tot += sc[c] * ef[c]; }
    float rinv = 1.0f / tot;
#pragma unroll
    for (int c = 0; c < 32; ++c) fctL[c * 128 + tid] = ef[c] * rinv;
  }

  const _Float16* Ag = P + ((size_t)b * Ss + (size_t)tm * 128) * Ss;
  const _Float16* Bg = Vt + ((size_t)b * Dd + (size_t)tn * 64) * Ss;

  int rowA[4], colA[4], offA[4];
#pragma unroll
  for (int i = 0; i < 4; ++i) {
    int se = (w * 4 + i) * 512 + L * 8;
    int row = se >> 6;
    int blk = (se >> 3) & 7;
    rowA[i] = row;
    colA[i] = (blk ^ (row & 7)) << 3;
    offA[i] = se;
  }
  int rowB[2], colB[2], offB[2];
#pragma unroll
  for (int i = 0; i < 2; ++i) {
    int se = (w * 2 + i) * 512 + L * 8;
    int row = se >> 6;
    int blk = (se >> 3) & 7;
    rowB[i] = row;
    colB[i] = (blk ^ (row & 7)) << 3;
    offB[i] = se;
  }

  f32x4 acc[4][2];
#pragma unroll
  for (int mt = 0; mt < 4; ++mt)
#pragma unroll
    for (int nt = 0; nt < 2; ++nt) acc[mt][nt] = (f32x4){0.f, 0.f, 0.f, 0.f};

  int g = L >> 4, lm = L & 15;

  for (int k0 = 0; k0 < Ss; k0 += 64) {
    __syncthreads();
#pragma unroll
    for (int i = 0; i < 4; ++i)
      gload_lds16(Ag + (size_t)rowA[i] * Ss + k0 + colA[i], lA + offA[i]);
#pragma unroll
    for (int i = 0; i < 2; ++i)
      gload_lds16(Bg + (size_t)rowB[i] * Ss + k0 + colB[i], lB + offB[i]);
    __syncthreads();
    _Float16 fh[4];
#pragma unroll
    for (int mt = 0; mt < 4; ++mt)
      fh[mt] = (_Float16)fctL[(k0 >> 6) * 128 + wm * 64 + mt * 16 + lm];
#pragma unroll
    for (int ds = 0; ds < 64; ds += 32) {
      half8 af[4], bf[2];
#pragma unroll
      for (int mt = 0; mt < 4; ++mt) {
        int row = wm * 64 + mt * 16 + lm;
        int blk = ((ds >> 3) + g) ^ (row & 7);
        af[mt] = *(const half8*)(lA + row * 64 + blk * 8);
#pragma unroll
        for (int j = 0; j < 8; ++j) af[mt][j] *= fh[mt];
      }
#pragma unroll
      for (int nt = 0; nt < 2; ++nt) {
        int row = wn * 32 + nt * 16 + lm;
        int blk = ((ds >> 3) + g) ^ (row & 7);
        bf[nt] = *(const half8*)(lB + row * 64 + blk * 8);
      }
#pragma unroll
      for (int mt = 0; mt < 4; ++mt)
#pragma unroll
        for (int nt = 0; nt < 2; ++nt)
          acc[mt][nt] = __builtin_amdgcn_mfma_f32_16x16x32_f16(af[mt], bf[nt], acc[mt][nt], 0, 0, 0);
    }
  }

#pragma unroll
  for (int mt = 0; mt < 4; ++mt) {
#pragma unroll
    for (int r = 0; r < 4; ++r) {
      int row_g = tm * 128 + wm * 64 + mt * 16 + g * 4 + r;
      float* Crow = C + ((size_t)b * Ss + row_g) * Dd + (size_t)tn * 64 + wn * 32 + lm;
#pragma unroll
      for (int nt = 0; nt < 2; ++nt) Crow[nt * 16] = acc[mt][nt][r];
    }
  }
}

extern "C" void kernel_launch(void* const* d_in, const int* in_sizes, int n_in,
                              void* d_out, int out_size, void* d_ws, size_t ws_size,
                              hipStream_t stream) {
  const float* enc = (const float*)d_in[0];
  const float* dec = (const float*)d_in[1];
  float* out = (float*)d_out;

  const size_t nElem = (size_t)Bb * Ss * Dd;  // 8388608
  const size_t nS = (size_t)Bb * Ss * Ss;     // 33554432

  _Float16* dec16 = (_Float16*)d_ws;
  _Float16* enc16 = dec16 + nElem;
  _Float16* encT = enc16 + nElem;
  _Float16* Sp = encT + nElem;
  half2_t* pms = (half2_t*)(Sp + nS);

  size_t need = nElem * 2 * 3 + nS * 2 + (size_t)Bb * Ss * 32 * 4;
  if (ws_size < need) return;

  static int g_k1_big = -1;
  if (g_k1_big < 0) {
    int ok = 0;
    (void)hipFuncSetAttribute(reinterpret_cast<const void*>(&k1_qk),
                              hipFuncAttributeMaxDynamicSharedMemorySize, 131072);
    hipFuncAttributes fa;
    if (hipFuncGetAttributes(&fa, reinterpret_cast<const void*>(&k1_qk)) == hipSuccess &&
        fa.maxDynamicSharedSizeBytes >= 131072) ok = 1;
    if (!ok) {
      int dev = 0, maxShm = 0;
      (void)hipGetDevice(&dev);
      if (hipDeviceGetAttribute(&maxShm, hipDeviceAttributeMaxSharedMemoryPerBlock, dev) ==
              hipSuccess && maxShm >= 131072) ok = 1;
    }
    g_k1_big = ok;
  }

  k0_prep<<<2048, 256, 0, stream>>>(enc, dec, enc16, encT, dec16);
  if (g_k1_big)
    k1_qk<<<512, 512, 131072, stream>>>(dec16, enc16, Sp, pms);
  else
    k1_qk_fb<<<2048, 256, 0, stream>>>(dec16, enc16, Sp, pms);
  k3_pv<<<1024, 256, 0, stream>>>(Sp, encT, pms, out);
}